// Round 5
// baseline (851.477 us; speedup 1.0000x reference)
//
#include <hip/hip_runtime.h>
#include <hip/hip_cooperative_groups.h>
#include <stdint.h>

namespace cg = cooperative_groups;

// Problem constants (static per reference)
#define S_TOK   8192
#define MODEL_D 1024
#define N_EXP   64
#define CAP     128         // max(ceil(8192/64*1.0), 8)
#define SHIFT   4096        // int(S * 0.5)
#define SLAB    (N_EXP * CAP)           // 8192 floats per token slab
#define CDSIZE  ((size_t)S_TOK * SLAB)  // 67108864
#define OUT_FILL4 33554448              // float4 count covering out[0..134217792)

#define GRID_BLOCKS 512                 // 2 blocks/CU — guaranteed co-resident
#define GEMM_BLOCKS 512
#define TPB         16                  // tokens per gemm block

// d_out layout (float32): [l_aux(1) | combine(CDSIZE) | dispatch(CDSIZE) | exp_counts(64) | unrouted(1)]
// Fill covers out[0..134217792); exp_counts[63] (idx 134217792) and unrouted
// (134217793) are outside the fill but written unconditionally by the scalar block.

// ws offsets (bytes)
#define OFF_EXPERT   0          // int[8192]
#define OFF_GATE     32768      // float[8192]   max-gate value (=1/Z)
#define OFF_KEY      65536      // uint[8192]    sortable importance key
#define OFF_KEY2     98304      // uint[8192]    (expert<<13)|pos
#define OFF_MEPART   131072     // float[512][64] per-block gate column sums
#define OFF_HIST     262144     // int[512][64]   per-block argmax histograms
#define OFF_WGT      393216     // float[256][64][4] repacked weights [d/4][e][d%4]

__device__ __forceinline__ unsigned f2key(float f) {
    // monotonic float->uint transform (ascending float == ascending uint)
    unsigned b = __float_as_uint(f);
    return (b & 0x80000000u) ? ~b : (b | 0x80000000u);
}

// ============================ device helpers (shared logic) ==================

__device__ __forceinline__ void repack_block(const float* __restrict__ wg,
                                             float* __restrict__ wgT4,
                                             int b, int tid) {
    // repack wg [64][1024] -> wgT4 [256][64][4] (b in [0,64))
    int id0 = b * 256 + tid;
#pragma unroll
    for (int i = 0; i < 4; ++i) {
        int id = id0 + i * 16384;
        int e = id >> 10;
        int d = id & 1023;
        wgT4[((d >> 2) * 64 + e) * 4 + (d & 3)] = wg[id];
    }
}

// ============================ cooperative single-kernel path =================

__global__ __launch_bounds__(256, 2) void k_all(
    const float* __restrict__ x, const float* __restrict__ wg,
    float* __restrict__ out, float* __restrict__ wgT4,
    int* __restrict__ expert_id, float* __restrict__ gate1,
    unsigned* __restrict__ keys, unsigned* __restrict__ key2,
    float* __restrict__ me_part, int* __restrict__ hist_part)
{
    __shared__ union {
        struct {                        // phase 1 (gemm)
            float xs[TPB][256];         // 16 KB x chunk tile
            float lg[TPB][65];          // logits, padded
            float mrow[TPB], zrow[TPB];
            int   exrow[TPB];
            int   hist[64];
            float mep[4][64];
        } g;
        uint4 k4[2048];                 // phases 2/3: all 8192 keys (32 KB)
        struct {                        // phase 2 scalar block
            float msum[4][64];
            int   hsum[4][64];
            float contrib[64];
            int   keep[64];
        } s;
    } sh;

    cg::grid_group grid = cg::this_grid();
    const int b   = blockIdx.x;
    const int tid = threadIdx.x;

    // ---- Phase 0: weight repack (blocks 0..63) + output zero-fill (all) ----
    if (b < 64) repack_block(wg, wgT4, b, tid);
    {
        const float4 z = make_float4(0.f, 0.f, 0.f, 0.f);
        float4* out4 = (float4*)out;
        for (size_t i = (size_t)b * 256 + tid; i < OUT_FILL4; i += (size_t)GRID_BLOCKS * 256)
            out4[i] = z;
    }
    grid.sync();

    // ---- Phase 1: gate GEMM + softmax/argmax/key + me/hist partials --------
    {
        const int lane = tid & 63;       // expert index
        const int wv   = tid >> 6;
        const int tok0 = b * TPB;
        const float4* xg  = (const float4*)x;
        const float4* wg4 = (const float4*)wgT4;

        float acc[4] = {0.f, 0.f, 0.f, 0.f};
        for (int chunk = 0; chunk < 4; ++chunk) {
            __syncthreads();
#pragma unroll
            for (int i = 0; i < 4; ++i) {
                int linear = tid + 256 * i;          // 0..1023
                int t  = linear >> 6;
                int c4 = linear & 63;
                ((float4*)sh.g.xs)[t * 64 + c4] =
                    xg[(size_t)(tok0 + t) * 256 + chunk * 64 + c4];
            }
            __syncthreads();
#pragma unroll 4
            for (int dd = 0; dd < 256; dd += 4) {
                int d = chunk * 256 + dd;
                float4 w = wg4[(d >> 2) * 64 + lane];     // coalesced
#pragma unroll
                for (int t = 0; t < 4; ++t) {
                    float4 xv = *(const float4*)&sh.g.xs[wv * 4 + t][dd];  // LDS broadcast
                    acc[t] = fmaf(xv.x, w.x, acc[t]);
                    acc[t] = fmaf(xv.y, w.y, acc[t]);
                    acc[t] = fmaf(xv.z, w.z, acc[t]);
                    acc[t] = fmaf(xv.w, w.w, acc[t]);
                }
            }
        }
#pragma unroll
        for (int t = 0; t < 4; ++t) sh.g.lg[wv * 4 + t][lane] = acc[t];
        __syncthreads();

        if (tid < 64) sh.g.hist[tid] = 0;
        if (tid < TPB) {
            const int t = tid;
            float m = sh.g.lg[t][0]; int am = 0;
            for (int e = 1; e < 64; ++e) {
                float v = sh.g.lg[t][e];
                if (v > m) { m = v; am = e; }   // strict >: first-occurrence argmax
            }
            float z = 0.f;
            for (int e = 0; e < 64; ++e) z += expf(sh.g.lg[t][e] - m);
            float rz = 1.0f / z;                // = max gate value
            sh.g.mrow[t] = m; sh.g.zrow[t] = rz; sh.g.exrow[t] = am;
            int sG = tok0 + t;
            expert_id[sG] = am;
            gate1[sG] = rz;
            keys[sG] = f2key(-rz);              // importance = -maxgate, ascending
        }
        __syncthreads();

        if (tid < TPB) atomicAdd(&sh.g.hist[sh.g.exrow[tid]], 1);
        {
            const int e = tid & 63, tg = tid >> 6;
            float p = 0.f;
            for (int t = tg; t < TPB; t += 4)
                p += expf(sh.g.lg[t][e] - sh.g.mrow[t]) * sh.g.zrow[t];
            sh.g.mep[tg][e] = p;
        }
        __syncthreads();

        if (tid < 64) {
            me_part[b * 64 + tid] = sh.g.mep[0][tid] + sh.g.mep[1][tid]
                                  + sh.g.mep[2][tid] + sh.g.mep[3][tid];
            hist_part[b * 64 + tid] = sh.g.hist[tid];
        }
    }
    grid.sync();

    // ---- Phase 2: global rank -> key2 (blocks 0..255); scalars (block 256) --
    if (b < 256) {
        const uint4* kg = (const uint4*)keys;
        for (int i = tid; i < 2048; i += 256) sh.k4[i] = kg[i];
        __syncthreads();

        const int sl = tid >> 3, part = tid & 7;
        const int sG = b * 32 + sl;
        const unsigned myk = ((const unsigned*)sh.k4)[sG];
        int cnt = 0;
        const int qbase = part * 256;
        for (int q = 0; q < 256; ++q) {
            int qq = (q + part) & 255;            // bank-phase swizzle
            uint4 v = sh.k4[qbase + qq];
            int j = (qbase + qq) * 4;
            cnt += (v.x < myk) || (v.x == myk && (j + 0) < sG);
            cnt += (v.y < myk) || (v.y == myk && (j + 1) < sG);
            cnt += (v.z < myk) || (v.z == myk && (j + 2) < sG);
            cnt += (v.w < myk) || (v.w == myk && (j + 3) < sG);
        }
        cnt += __shfl_down(cnt, 4);
        cnt += __shfl_down(cnt, 2);
        cnt += __shfl_down(cnt, 1);
        if (part == 0) {
            int pos = (cnt + SHIFT) & (S_TOK - 1);
            key2[sG] = ((unsigned)expert_id[sG] << 13) | (unsigned)pos;
        }
    } else if (b == 256) {
        // dropped = S - sum_e min(count_e, CAP) (within-expert ranks are a bijection)
        const int e = tid & 63, qt = tid >> 6;
        float ms = 0.f; int hs = 0;
        for (int p = qt * 128; p < qt * 128 + 128; ++p) {
            ms += me_part[p * 64 + e];
            hs += hist_part[p * 64 + e];
        }
        sh.s.msum[qt][e] = ms; sh.s.hsum[qt][e] = hs;
        __syncthreads();
        if (tid < 64) {
            float m = sh.s.msum[0][tid] + sh.s.msum[1][tid]
                    + sh.s.msum[2][tid] + sh.s.msum[3][tid];
            int   h = sh.s.hsum[0][tid] + sh.s.hsum[1][tid]
                    + sh.s.hsum[2][tid] + sh.s.hsum[3][tid];
            out[1 + 2 * CDSIZE + tid] = (float)h;                          // exp_counts
            sh.s.contrib[tid] = (m * (1.0f / S_TOK)) * ((float)h * (1.0f / S_TOK));
            sh.s.keep[tid] = (h < CAP) ? h : CAP;
        }
        __syncthreads();
        if (tid == 0) {
            float sum = 0.f; int kept = 0;
            for (int i = 0; i < 64; ++i) { sum += sh.s.contrib[i]; kept += sh.s.keep[i]; }
            out[0] = sum * (float)N_EXP * 0.01f;                           // l_aux
            out[1 + 2 * CDSIZE + 64] = (float)(S_TOK - kept) * (1.0f / S_TOK); // unrouted
        }
    }
    grid.sync();

    // ---- Phase 3: within-expert loc + one-hot scatter -----------------------
    if (b < 256) {
        const uint4* kg = (const uint4*)key2;
        for (int i = tid; i < 2048; i += 256) sh.k4[i] = kg[i];
        __syncthreads();

        const int sl = tid >> 3, part = tid & 7;
        const int sG = b * 32 + sl;
        const unsigned myk = ((const unsigned*)sh.k4)[sG];
        const unsigned lo = myk & ~8191u;   // expert<<13
        int cnt = 0;
        const int qbase = part * 256;
        for (int q = 0; q < 256; ++q) {
            int qq = (q + part) & 255;
            uint4 v = sh.k4[qbase + qq];
            cnt += (v.x >= lo) && (v.x < myk);
            cnt += (v.y >= lo) && (v.y < myk);
            cnt += (v.z >= lo) && (v.z < myk);
            cnt += (v.w >= lo) && (v.w < myk);
        }
        cnt += __shfl_down(cnt, 4);
        cnt += __shfl_down(cnt, 2);
        cnt += __shfl_down(cnt, 1);
        if (part == 0 && cnt < CAP) {
            unsigned e = myk >> 13;
            size_t idx = 1 + (size_t)sG * SLAB + (size_t)e * CAP + (unsigned)cnt;
            out[idx] = gate1[sG];            // combine_weights one-hot
            out[idx + CDSIZE] = 1.0f;        // dispatch_mask one-hot
        }
    }
}

// ============================ fallback path (R3-proven, 4 kernels) ===========

__global__ __launch_bounds__(256) void k0_repack(const float* __restrict__ wg,
                                                 float* __restrict__ wgT4) {
    repack_block(wg, wgT4, blockIdx.x, threadIdx.x);
}

__global__ __launch_bounds__(256) void k1_fill_gemm(
    const float* __restrict__ x, const float* __restrict__ wgT4,
    float* __restrict__ out,
    int* __restrict__ expert_id, float* __restrict__ gate1,
    unsigned* __restrict__ keys, float* __restrict__ me_part,
    int* __restrict__ hist_part)
{
    const int b = blockIdx.x;
    if (b >= GEMM_BLOCKS) {
        const float4 z = make_float4(0.f, 0.f, 0.f, 0.f);
        float4* out4 = (float4*)out;
        size_t i = (size_t)(b - GEMM_BLOCKS) * 256 + threadIdx.x;
        for (; i < OUT_FILL4; i += (size_t)8192 * 256) out4[i] = z;
        return;
    }

    __shared__ float xs[TPB][256];
    __shared__ float lg[TPB][65];
    __shared__ float mrow[TPB], zrow[TPB];
    __shared__ int   exrow[TPB];
    __shared__ int   hist[64];
    __shared__ float mep[4][64];

    const int tid  = threadIdx.x;
    const int lane = tid & 63;
    const int wv   = tid >> 6;
    const int tok0 = b * TPB;

    const float4* xg  = (const float4*)x;
    const float4* wg4 = (const float4*)wgT4;

    float acc[4] = {0.f, 0.f, 0.f, 0.f};
    for (int chunk = 0; chunk < 4; ++chunk) {
        __syncthreads();
#pragma unroll
        for (int i = 0; i < 4; ++i) {
            int linear = tid + 256 * i;
            int t  = linear >> 6;
            int c4 = linear & 63;
            ((float4*)xs)[t * 64 + c4] = xg[(size_t)(tok0 + t) * 256 + chunk * 64 + c4];
        }
        __syncthreads();
#pragma unroll 4
        for (int dd = 0; dd < 256; dd += 4) {
            int d = chunk * 256 + dd;
            float4 w = wg4[(d >> 2) * 64 + lane];
#pragma unroll
            for (int t = 0; t < 4; ++t) {
                float4 xv = *(const float4*)&xs[wv * 4 + t][dd];
                acc[t] = fmaf(xv.x, w.x, acc[t]);
                acc[t] = fmaf(xv.y, w.y, acc[t]);
                acc[t] = fmaf(xv.z, w.z, acc[t]);
                acc[t] = fmaf(xv.w, w.w, acc[t]);
            }
        }
    }
#pragma unroll
    for (int t = 0; t < 4; ++t) lg[wv * 4 + t][lane] = acc[t];
    __syncthreads();

    if (tid < 64) hist[tid] = 0;
    if (tid < TPB) {
        const int t = tid;
        float m = lg[t][0]; int am = 0;
        for (int e = 1; e < 64; ++e) {
            float v = lg[t][e];
            if (v > m) { m = v; am = e; }
        }
        float z = 0.f;
        for (int e = 0; e < 64; ++e) z += expf(lg[t][e] - m);
        float rz = 1.0f / z;
        mrow[t] = m; zrow[t] = rz; exrow[t] = am;
        int sG = tok0 + t;
        expert_id[sG] = am;
        gate1[sG] = rz;
        keys[sG] = f2key(-rz);
    }
    __syncthreads();

    if (tid < TPB) atomicAdd(&hist[exrow[tid]], 1);
    {
        const int e = tid & 63, tg = tid >> 6;
        float p = 0.f;
        for (int t = tg; t < TPB; t += 4) p += expf(lg[t][e] - mrow[t]) * zrow[t];
        mep[tg][e] = p;
    }
    __syncthreads();

    if (tid < 64) {
        me_part[b * 64 + tid] = mep[0][tid] + mep[1][tid] + mep[2][tid] + mep[3][tid];
        hist_part[b * 64 + tid] = hist[tid];
    }
}

__global__ __launch_bounds__(256) void k2_rank_scalars(
    const unsigned* __restrict__ keys, const int* __restrict__ expert_id,
    const float* __restrict__ me_part, const int* __restrict__ hist_part,
    unsigned* __restrict__ key2, float* __restrict__ out)
{
    const int tid = threadIdx.x;
    if (blockIdx.x == 256) {
        __shared__ float msum[4][64];
        __shared__ int   hsum[4][64];
        __shared__ float contrib[64];
        __shared__ int   keep[64];
        const int e = tid & 63, qt = tid >> 6;
        float ms = 0.f; int hs = 0;
        for (int p = qt * 128; p < qt * 128 + 128; ++p) {
            ms += me_part[p * 64 + e];
            hs += hist_part[p * 64 + e];
        }
        msum[qt][e] = ms; hsum[qt][e] = hs;
        __syncthreads();
        if (tid < 64) {
            float m = msum[0][tid] + msum[1][tid] + msum[2][tid] + msum[3][tid];
            int   h = hsum[0][tid] + hsum[1][tid] + hsum[2][tid] + hsum[3][tid];
            out[1 + 2 * CDSIZE + tid] = (float)h;
            contrib[tid] = (m * (1.0f / S_TOK)) * ((float)h * (1.0f / S_TOK));
            keep[tid] = (h < CAP) ? h : CAP;
        }
        __syncthreads();
        if (tid == 0) {
            float sum = 0.f; int kept = 0;
            for (int i = 0; i < 64; ++i) { sum += contrib[i]; kept += keep[i]; }
            out[0] = sum * (float)N_EXP * 0.01f;
            out[1 + 2 * CDSIZE + 64] = (float)(S_TOK - kept) * (1.0f / S_TOK);
        }
        return;
    }

    __shared__ uint4 k4[2048];
    const uint4* kg = (const uint4*)keys;
    for (int i = tid; i < 2048; i += 256) k4[i] = kg[i];
    __syncthreads();

    const int sl = tid >> 3, part = tid & 7;
    const int sG = blockIdx.x * 32 + sl;
    const unsigned myk = ((const unsigned*)k4)[sG];
    int cnt = 0;
    const int qbase = part * 256;
    for (int q = 0; q < 256; ++q) {
        int qq = (q + part) & 255;
        uint4 v = k4[qbase + qq];
        int j = (qbase + qq) * 4;
        cnt += (v.x < myk) || (v.x == myk && (j + 0) < sG);
        cnt += (v.y < myk) || (v.y == myk && (j + 1) < sG);
        cnt += (v.z < myk) || (v.z == myk && (j + 2) < sG);
        cnt += (v.w < myk) || (v.w == myk && (j + 3) < sG);
    }
    cnt += __shfl_down(cnt, 4);
    cnt += __shfl_down(cnt, 2);
    cnt += __shfl_down(cnt, 1);
    if (part == 0) {
        int pos = (cnt + SHIFT) & (S_TOK - 1);
        key2[sG] = ((unsigned)expert_id[sG] << 13) | (unsigned)pos;
    }
}

__global__ __launch_bounds__(256) void k3_loc_scatter(const unsigned* __restrict__ key2,
                                                      const float* __restrict__ gate1,
                                                      float* __restrict__ out)
{
    __shared__ uint4 k4[2048];
    const int tid = threadIdx.x;
    const uint4* kg = (const uint4*)key2;
    for (int i = tid; i < 2048; i += 256) k4[i] = kg[i];
    __syncthreads();

    const int sl = tid >> 3, part = tid & 7;
    const int sG = blockIdx.x * 32 + sl;
    const unsigned myk = ((const unsigned*)k4)[sG];
    const unsigned lo = myk & ~8191u;
    int cnt = 0;
    const int qbase = part * 256;
    for (int q = 0; q < 256; ++q) {
        int qq = (q + part) & 255;
        uint4 v = k4[qbase + qq];
        cnt += (v.x >= lo) && (v.x < myk);
        cnt += (v.y >= lo) && (v.y < myk);
        cnt += (v.z >= lo) && (v.z < myk);
        cnt += (v.w >= lo) && (v.w < myk);
    }
    cnt += __shfl_down(cnt, 4);
    cnt += __shfl_down(cnt, 2);
    cnt += __shfl_down(cnt, 1);
    if (part == 0 && cnt < CAP) {
        unsigned e = myk >> 13;
        size_t idx = 1 + (size_t)sG * SLAB + (size_t)e * CAP + (unsigned)cnt;
        out[idx] = gate1[sG];
        out[idx + CDSIZE] = 1.0f;
    }
}

extern "C" void kernel_launch(void* const* d_in, const int* in_sizes, int n_in,
                              void* d_out, int out_size, void* d_ws, size_t ws_size,
                              hipStream_t stream) {
    (void)in_sizes; (void)n_in; (void)out_size; (void)ws_size;
    const float* x  = (const float*)d_in[0];
    const float* wg = (const float*)d_in[1];
    float* out = (float*)d_out;
    char* ws = (char*)d_ws;

    float*    wgT4      = (float*)(ws + OFF_WGT);
    int*      expert_id = (int*)(ws + OFF_EXPERT);
    float*    gate1     = (float*)(ws + OFF_GATE);
    unsigned* keys      = (unsigned*)(ws + OFF_KEY);
    unsigned* key2      = (unsigned*)(ws + OFF_KEY2);
    float*    me_part   = (float*)(ws + OFF_MEPART);
    int*      hist_part = (int*)(ws + OFF_HIST);

    void* args[] = { (void*)&x, (void*)&wg, (void*)&out, (void*)&wgT4,
                     (void*)&expert_id, (void*)&gate1, (void*)&keys, (void*)&key2,
                     (void*)&me_part, (void*)&hist_part };
    hipError_t err = hipLaunchCooperativeKernel((const void*)k_all, dim3(GRID_BLOCKS),
                                                dim3(256), args, 0, stream);
    if (err != hipSuccess) {
        (void)hipGetLastError();   // clear sticky error, use proven 4-node chain
        hipLaunchKernelGGL(k0_repack,       dim3(64),                 dim3(256), 0, stream, wg, wgT4);
        hipLaunchKernelGGL(k1_fill_gemm,    dim3(GEMM_BLOCKS + 8192), dim3(256), 0, stream,
                           x, wgT4, out, expert_id, gate1, keys, me_part, hist_part);
        hipLaunchKernelGGL(k2_rank_scalars, dim3(257),                dim3(256), 0, stream,
                           keys, expert_id, me_part, hist_part, key2, out);
        hipLaunchKernelGGL(k3_loc_scatter,  dim3(256),                dim3(256), 0, stream,
                           key2, gate1, out);
    }
}

// Round 7
// 801.963 us; speedup vs baseline: 1.0617x; 1.0617x over previous
//
#include <hip/hip_runtime.h>
#include <hip/hip_cooperative_groups.h>
#include <stdint.h>

namespace cg = cooperative_groups;

// Problem constants (static per reference)
#define S_TOK   8192
#define MODEL_D 1024
#define N_EXP   64
#define CAP     128         // max(ceil(8192/64*1.0), 8)
#define SHIFT   4096        // int(S * 0.5)
#define SLAB    (N_EXP * CAP)           // 8192 floats per token slab
#define CDSIZE  ((size_t)S_TOK * SLAB)  // 67108864
#define OUT_FILL4 33554448              // float4 count covering out[0..134217792)

#define GRID_BLOCKS 512                 // 2 blocks/CU — proven co-resident (R5)
#define GEMM_BLOCKS 512
#define TPB         16                  // tokens per gemm block

// native clang vector type: __builtin_nontemporal_store requires it
typedef float nf4 __attribute__((ext_vector_type(4)));

// d_out layout (float32): [l_aux(1) | combine(CDSIZE) | dispatch(CDSIZE) | exp_counts(64) | unrouted(1)]
// Fill covers out[0..134217792); exp_counts[63] + unrouted are written
// unconditionally by the scalar block.

// ws offsets (bytes)
#define OFF_EXPERT   0          // int[8192]
#define OFF_GATE     32768      // float[8192]   max-gate value (=1/Z)
#define OFF_KEY      65536      // uint[8192]    sortable importance key
#define OFF_KEY2     98304      // uint[8192]    (expert<<13)|pos
#define OFF_MEPART   131072     // float[512][64] per-block gate column sums
#define OFF_HIST     262144     // int[512][64]   per-block argmax histograms
#define OFF_WGT      393216     // float[256][64][4] repacked weights [d/4][e][d%4]

__device__ __forceinline__ unsigned f2key(float f) {
    // monotonic float->uint transform (ascending float == ascending uint)
    unsigned b = __float_as_uint(f);
    return (b & 0x80000000u) ? ~b : (b | 0x80000000u);
}

__device__ __forceinline__ void repack_block(const float* __restrict__ wg,
                                             float* __restrict__ wgT4,
                                             int b, int tid) {
    // repack wg [64][1024] -> wgT4 [256][64][4] (b in [0,64))
    int id0 = b * 256 + tid;
#pragma unroll
    for (int i = 0; i < 4; ++i) {
        int id = id0 + i * 16384;
        int e = id >> 10;
        int d = id & 1023;
        wgT4[((d >> 2) * 64 + e) * 4 + (d & 3)] = wg[id];
    }
}

// Node 0: weight repack (tiny, ~2 µs). Keeps the coop kernel at 2 grid syncs.
__global__ __launch_bounds__(256) void k0_repack(const float* __restrict__ wg,
                                                 float* __restrict__ wgT4) {
    repack_block(wg, wgT4, blockIdx.x, threadIdx.x);
}

// ============================ cooperative main kernel ========================
// Phase 0: gemm (all 512 blocks) then nt contiguous fill (all blocks)
// sync -> Phase 1: rank (blocks 0..255) + scalars (block 256)
// sync -> Phase 2: within-expert loc + one-hot scatter (blocks 0..255)
__global__ __launch_bounds__(256, 2) void k_all(
    const float* __restrict__ x, const float* __restrict__ wgT4,
    float* __restrict__ out,
    int* __restrict__ expert_id, float* __restrict__ gate1,
    unsigned* __restrict__ keys, unsigned* __restrict__ key2,
    float* __restrict__ me_part, int* __restrict__ hist_part)
{
    __shared__ union {
        struct {                        // phase 0 (gemm)
            float xs[TPB][256];         // 16 KB x chunk tile
            float lg[TPB][65];          // logits, padded
            float mrow[TPB], zrow[TPB];
            int   exrow[TPB];
            int   hist[64];
            float mep[4][64];
        } g;
        uint4 k4[2048];                 // phases 1/2: all 8192 keys (32 KB)
        struct {                        // phase 1 scalar block
            float msum[4][64];
            int   hsum[4][64];
            float contrib[64];
            int   keep[64];
        } s;
    } sh;

    cg::grid_group grid = cg::this_grid();
    const int b   = blockIdx.x;
    const int tid = threadIdx.x;

    // ---- Phase 0a: gate GEMM + softmax/argmax/key + me/hist partials -------
    {
        const int lane = tid & 63;       // expert index
        const int wv   = tid >> 6;
        const int tok0 = b * TPB;
        const float4* xg  = (const float4*)x;
        const float4* wg4 = (const float4*)wgT4;

        float acc[4] = {0.f, 0.f, 0.f, 0.f};
        for (int chunk = 0; chunk < 4; ++chunk) {
            __syncthreads();
#pragma unroll
            for (int i = 0; i < 4; ++i) {
                int linear = tid + 256 * i;          // 0..1023
                int t  = linear >> 6;
                int c4 = linear & 63;
                ((float4*)sh.g.xs)[t * 64 + c4] =
                    xg[(size_t)(tok0 + t) * 256 + chunk * 64 + c4];
            }
            __syncthreads();
#pragma unroll 4
            for (int dd = 0; dd < 256; dd += 4) {
                int d = chunk * 256 + dd;
                float4 w = wg4[(d >> 2) * 64 + lane];     // coalesced
#pragma unroll
                for (int t = 0; t < 4; ++t) {
                    float4 xv = *(const float4*)&sh.g.xs[wv * 4 + t][dd];  // LDS broadcast
                    acc[t] = fmaf(xv.x, w.x, acc[t]);
                    acc[t] = fmaf(xv.y, w.y, acc[t]);
                    acc[t] = fmaf(xv.z, w.z, acc[t]);
                    acc[t] = fmaf(xv.w, w.w, acc[t]);
                }
            }
        }
#pragma unroll
        for (int t = 0; t < 4; ++t) sh.g.lg[wv * 4 + t][lane] = acc[t];
        __syncthreads();

        if (tid < 64) sh.g.hist[tid] = 0;
        if (tid < TPB) {
            const int t = tid;
            float m = sh.g.lg[t][0]; int am = 0;
            for (int e = 1; e < 64; ++e) {
                float v = sh.g.lg[t][e];
                if (v > m) { m = v; am = e; }   // strict >: first-occurrence argmax
            }
            float z = 0.f;
            for (int e = 0; e < 64; ++e) z += expf(sh.g.lg[t][e] - m);
            float rz = 1.0f / z;                // = max gate value
            sh.g.mrow[t] = m; sh.g.zrow[t] = rz; sh.g.exrow[t] = am;
            int sG = tok0 + t;
            expert_id[sG] = am;
            gate1[sG] = rz;
            keys[sG] = f2key(-rz);              // importance = -maxgate, ascending
        }
        __syncthreads();

        if (tid < TPB) atomicAdd(&sh.g.hist[sh.g.exrow[tid]], 1);
        {
            const int e = tid & 63, tg = tid >> 6;
            float p = 0.f;
            for (int t = tg; t < TPB; t += 4)
                p += expf(sh.g.lg[t][e] - sh.g.mrow[t]) * sh.g.zrow[t];
            sh.g.mep[tg][e] = p;
        }
        __syncthreads();

        if (tid < 64) {
            me_part[b * 64 + tid] = sh.g.mep[0][tid] + sh.g.mep[1][tid]
                                  + sh.g.mep[2][tid] + sh.g.mep[3][tid];
            hist_part[b * 64 + tid] = sh.g.hist[tid];
        }
    }

    // ---- Phase 0b: non-temporal contiguous zero-fill of out ----------------
    // Block b owns float4 span [b*65536, (b+1)*65536): contiguous 1 MB stream
    // (4 KB per iteration), start rotated by b so blocks spread across DRAM
    // channels at every instant. nt bypasses L2 write-back.
    {
        const nf4 z = {0.f, 0.f, 0.f, 0.f};
        nf4* out4 = (nf4*)out;
        const size_t base = (size_t)b * 65536;
        for (int it = 0; it < 256; ++it) {
            int itr = (it + b) & 255;            // channel phase rotation
            __builtin_nontemporal_store(z, &out4[base + (size_t)itr * 256 + tid]);
        }
        if (b == 511 && tid < 16)                // tail: OUT_FILL4 - 512*65536 = 16
            __builtin_nontemporal_store(z, &out4[(size_t)512 * 65536 + tid]);
    }
    grid.sync();

    // ---- Phase 1: global rank -> key2 (blocks 0..255); scalars (block 256) --
    if (b < 256) {
        const uint4* kg = (const uint4*)keys;
        for (int i = tid; i < 2048; i += 256) sh.k4[i] = kg[i];
        __syncthreads();

        const int sl = tid >> 3, part = tid & 7;
        const int sG = b * 32 + sl;
        const unsigned myk = ((const unsigned*)sh.k4)[sG];
        int cnt = 0;
        const int qbase = part * 256;
        for (int q = 0; q < 256; ++q) {
            int qq = (q + part) & 255;            // bank-phase swizzle
            uint4 v = sh.k4[qbase + qq];
            int j = (qbase + qq) * 4;
            cnt += (v.x < myk) || (v.x == myk && (j + 0) < sG);
            cnt += (v.y < myk) || (v.y == myk && (j + 1) < sG);
            cnt += (v.z < myk) || (v.z == myk && (j + 2) < sG);
            cnt += (v.w < myk) || (v.w == myk && (j + 3) < sG);
        }
        cnt += __shfl_down(cnt, 4);
        cnt += __shfl_down(cnt, 2);
        cnt += __shfl_down(cnt, 1);
        if (part == 0) {
            int pos = (cnt + SHIFT) & (S_TOK - 1);
            key2[sG] = ((unsigned)expert_id[sG] << 13) | (unsigned)pos;
        }
    } else if (b == 256) {
        // dropped = S - sum_e min(count_e, CAP) (within-expert ranks are a bijection)
        const int e = tid & 63, qt = tid >> 6;
        float ms = 0.f; int hs = 0;
        for (int p = qt * 128; p < qt * 128 + 128; ++p) {
            ms += me_part[p * 64 + e];
            hs += hist_part[p * 64 + e];
        }
        sh.s.msum[qt][e] = ms; sh.s.hsum[qt][e] = hs;
        __syncthreads();
        if (tid < 64) {
            float m = sh.s.msum[0][tid] + sh.s.msum[1][tid]
                    + sh.s.msum[2][tid] + sh.s.msum[3][tid];
            int   h = sh.s.hsum[0][tid] + sh.s.hsum[1][tid]
                    + sh.s.hsum[2][tid] + sh.s.hsum[3][tid];
            out[1 + 2 * CDSIZE + tid] = (float)h;                          // exp_counts
            sh.s.contrib[tid] = (m * (1.0f / S_TOK)) * ((float)h * (1.0f / S_TOK));
            sh.s.keep[tid] = (h < CAP) ? h : CAP;
        }
        __syncthreads();
        if (tid == 0) {
            float sum = 0.f; int kept = 0;
            for (int i = 0; i < 64; ++i) { sum += sh.s.contrib[i]; kept += sh.s.keep[i]; }
            out[0] = sum * (float)N_EXP * 0.01f;                           // l_aux
            out[1 + 2 * CDSIZE + 64] = (float)(S_TOK - kept) * (1.0f / S_TOK); // unrouted
        }
    }
    grid.sync();

    // ---- Phase 2: within-expert loc + one-hot scatter -----------------------
    if (b < 256) {
        const uint4* kg = (const uint4*)key2;
        for (int i = tid; i < 2048; i += 256) sh.k4[i] = kg[i];
        __syncthreads();

        const int sl = tid >> 3, part = tid & 7;
        const int sG = b * 32 + sl;
        const unsigned myk = ((const unsigned*)sh.k4)[sG];
        const unsigned lo = myk & ~8191u;   // expert<<13
        int cnt = 0;
        const int qbase = part * 256;
        for (int q = 0; q < 256; ++q) {
            int qq = (q + part) & 255;
            uint4 v = sh.k4[qbase + qq];
            cnt += (v.x >= lo) && (v.x < myk);
            cnt += (v.y >= lo) && (v.y < myk);
            cnt += (v.z >= lo) && (v.z < myk);
            cnt += (v.w >= lo) && (v.w < myk);
        }
        cnt += __shfl_down(cnt, 4);
        cnt += __shfl_down(cnt, 2);
        cnt += __shfl_down(cnt, 1);
        if (part == 0 && cnt < CAP) {
            unsigned e = myk >> 13;
            size_t idx = 1 + (size_t)sG * SLAB + (size_t)e * CAP + (unsigned)cnt;
            out[idx] = gate1[sG];            // combine_weights one-hot
            out[idx + CDSIZE] = 1.0f;        // dispatch_mask one-hot
        }
    }
}

// ============================ fallback path (R3-proven) ======================

__global__ __launch_bounds__(256) void k1_fill_gemm(
    const float* __restrict__ x, const float* __restrict__ wgT4,
    float* __restrict__ out,
    int* __restrict__ expert_id, float* __restrict__ gate1,
    unsigned* __restrict__ keys, float* __restrict__ me_part,
    int* __restrict__ hist_part)
{
    const int b = blockIdx.x;
    if (b >= GEMM_BLOCKS) {
        const nf4 z = {0.f, 0.f, 0.f, 0.f};
        nf4* out4 = (nf4*)out;
        size_t i = (size_t)(b - GEMM_BLOCKS) * 256 + threadIdx.x;
        for (; i < OUT_FILL4; i += (size_t)8192 * 256)
            __builtin_nontemporal_store(z, &out4[i]);
        return;
    }

    __shared__ float xs[TPB][256];
    __shared__ float lg[TPB][65];
    __shared__ float mrow[TPB], zrow[TPB];
    __shared__ int   exrow[TPB];
    __shared__ int   hist[64];
    __shared__ float mep[4][64];

    const int tid  = threadIdx.x;
    const int lane = tid & 63;
    const int wv   = tid >> 6;
    const int tok0 = b * TPB;

    const float4* xg  = (const float4*)x;
    const float4* wg4 = (const float4*)wgT4;

    float acc[4] = {0.f, 0.f, 0.f, 0.f};
    for (int chunk = 0; chunk < 4; ++chunk) {
        __syncthreads();
#pragma unroll
        for (int i = 0; i < 4; ++i) {
            int linear = tid + 256 * i;
            int t  = linear >> 6;
            int c4 = linear & 63;
            ((float4*)xs)[t * 64 + c4] = xg[(size_t)(tok0 + t) * 256 + chunk * 64 + c4];
        }
        __syncthreads();
#pragma unroll 4
        for (int dd = 0; dd < 256; dd += 4) {
            int d = chunk * 256 + dd;
            float4 w = wg4[(d >> 2) * 64 + lane];
#pragma unroll
            for (int t = 0; t < 4; ++t) {
                float4 xv = *(const float4*)&xs[wv * 4 + t][dd];
                acc[t] = fmaf(xv.x, w.x, acc[t]);
                acc[t] = fmaf(xv.y, w.y, acc[t]);
                acc[t] = fmaf(xv.z, w.z, acc[t]);
                acc[t] = fmaf(xv.w, w.w, acc[t]);
            }
        }
    }
#pragma unroll
    for (int t = 0; t < 4; ++t) lg[wv * 4 + t][lane] = acc[t];
    __syncthreads();

    if (tid < 64) hist[tid] = 0;
    if (tid < TPB) {
        const int t = tid;
        float m = lg[t][0]; int am = 0;
        for (int e = 1; e < 64; ++e) {
            float v = lg[t][e];
            if (v > m) { m = v; am = e; }
        }
        float z = 0.f;
        for (int e = 0; e < 64; ++e) z += expf(lg[t][e] - m);
        float rz = 1.0f / z;
        mrow[t] = m; zrow[t] = rz; exrow[t] = am;
        int sG = tok0 + t;
        expert_id[sG] = am;
        gate1[sG] = rz;
        keys[sG] = f2key(-rz);
    }
    __syncthreads();

    if (tid < TPB) atomicAdd(&hist[exrow[tid]], 1);
    {
        const int e = tid & 63, tg = tid >> 6;
        float p = 0.f;
        for (int t = tg; t < TPB; t += 4) p += expf(lg[t][e] - mrow[t]) * zrow[t];
        mep[tg][e] = p;
    }
    __syncthreads();

    if (tid < 64) {
        me_part[b * 64 + tid] = mep[0][tid] + mep[1][tid] + mep[2][tid] + mep[3][tid];
        hist_part[b * 64 + tid] = hist[tid];
    }
}

__global__ __launch_bounds__(256) void k2_rank_scalars(
    const unsigned* __restrict__ keys, const int* __restrict__ expert_id,
    const float* __restrict__ me_part, const int* __restrict__ hist_part,
    unsigned* __restrict__ key2, float* __restrict__ out)
{
    const int tid = threadIdx.x;
    if (blockIdx.x == 256) {
        __shared__ float msum[4][64];
        __shared__ int   hsum[4][64];
        __shared__ float contrib[64];
        __shared__ int   keep[64];
        const int e = tid & 63, qt = tid >> 6;
        float ms = 0.f; int hs = 0;
        for (int p = qt * 128; p < qt * 128 + 128; ++p) {
            ms += me_part[p * 64 + e];
            hs += hist_part[p * 64 + e];
        }
        msum[qt][e] = ms; hsum[qt][e] = hs;
        __syncthreads();
        if (tid < 64) {
            float m = msum[0][tid] + msum[1][tid] + msum[2][tid] + msum[3][tid];
            int   h = hsum[0][tid] + hsum[1][tid] + hsum[2][tid] + hsum[3][tid];
            out[1 + 2 * CDSIZE + tid] = (float)h;
            contrib[tid] = (m * (1.0f / S_TOK)) * ((float)h * (1.0f / S_TOK));
            keep[tid] = (h < CAP) ? h : CAP;
        }
        __syncthreads();
        if (tid == 0) {
            float sum = 0.f; int kept = 0;
            for (int i = 0; i < 64; ++i) { sum += contrib[i]; kept += keep[i]; }
            out[0] = sum * (float)N_EXP * 0.01f;
            out[1 + 2 * CDSIZE + 64] = (float)(S_TOK - kept) * (1.0f / S_TOK);
        }
        return;
    }

    __shared__ uint4 k4[2048];
    const uint4* kg = (const uint4*)keys;
    for (int i = tid; i < 2048; i += 256) k4[i] = kg[i];
    __syncthreads();

    const int sl = tid >> 3, part = tid & 7;
    const int sG = blockIdx.x * 32 + sl;
    const unsigned myk = ((const unsigned*)k4)[sG];
    int cnt = 0;
    const int qbase = part * 256;
    for (int q = 0; q < 256; ++q) {
        int qq = (q + part) & 255;
        uint4 v = k4[qbase + qq];
        int j = (qbase + qq) * 4;
        cnt += (v.x < myk) || (v.x == myk && (j + 0) < sG);
        cnt += (v.y < myk) || (v.y == myk && (j + 1) < sG);
        cnt += (v.z < myk) || (v.z == myk && (j + 2) < sG);
        cnt += (v.w < myk) || (v.w == myk && (j + 3) < sG);
    }
    cnt += __shfl_down(cnt, 4);
    cnt += __shfl_down(cnt, 2);
    cnt += __shfl_down(cnt, 1);
    if (part == 0) {
        int pos = (cnt + SHIFT) & (S_TOK - 1);
        key2[sG] = ((unsigned)expert_id[sG] << 13) | (unsigned)pos;
    }
}

__global__ __launch_bounds__(256) void k3_loc_scatter(const unsigned* __restrict__ key2,
                                                      const float* __restrict__ gate1,
                                                      float* __restrict__ out)
{
    __shared__ uint4 k4[2048];
    const int tid = threadIdx.x;
    const uint4* kg = (const uint4*)key2;
    for (int i = tid; i < 2048; i += 256) k4[i] = kg[i];
    __syncthreads();

    const int sl = tid >> 3, part = tid & 7;
    const int sG = blockIdx.x * 32 + sl;
    const unsigned myk = ((const unsigned*)k4)[sG];
    const unsigned lo = myk & ~8191u;
    int cnt = 0;
    const int qbase = part * 256;
    for (int q = 0; q < 256; ++q) {
        int qq = (q + part) & 255;
        uint4 v = k4[qbase + qq];
        cnt += (v.x >= lo) && (v.x < myk);
        cnt += (v.y >= lo) && (v.y < myk);
        cnt += (v.z >= lo) && (v.z < myk);
        cnt += (v.w >= lo) && (v.w < myk);
    }
    cnt += __shfl_down(cnt, 4);
    cnt += __shfl_down(cnt, 2);
    cnt += __shfl_down(cnt, 1);
    if (part == 0 && cnt < CAP) {
        unsigned e = myk >> 13;
        size_t idx = 1 + (size_t)sG * SLAB + (size_t)e * CAP + (unsigned)cnt;
        out[idx] = gate1[sG];
        out[idx + CDSIZE] = 1.0f;
    }
}

extern "C" void kernel_launch(void* const* d_in, const int* in_sizes, int n_in,
                              void* d_out, int out_size, void* d_ws, size_t ws_size,
                              hipStream_t stream) {
    (void)in_sizes; (void)n_in; (void)out_size; (void)ws_size;
    const float* x  = (const float*)d_in[0];
    const float* wg = (const float*)d_in[1];
    float* out = (float*)d_out;
    char* ws = (char*)d_ws;

    float*    wgT4      = (float*)(ws + OFF_WGT);
    int*      expert_id = (int*)(ws + OFF_EXPERT);
    float*    gate1     = (float*)(ws + OFF_GATE);
    unsigned* keys      = (unsigned*)(ws + OFF_KEY);
    unsigned* key2      = (unsigned*)(ws + OFF_KEY2);
    float*    me_part   = (float*)(ws + OFF_MEPART);
    int*      hist_part = (int*)(ws + OFF_HIST);

    hipLaunchKernelGGL(k0_repack, dim3(64), dim3(256), 0, stream, wg, wgT4);

    void* args[] = { (void*)&x, (void*)&wgT4, (void*)&out,
                     (void*)&expert_id, (void*)&gate1, (void*)&keys, (void*)&key2,
                     (void*)&me_part, (void*)&hist_part };
    hipError_t err = hipLaunchCooperativeKernel((const void*)k_all, dim3(GRID_BLOCKS),
                                                dim3(256), args, 0, stream);
    if (err != hipSuccess) {
        (void)hipGetLastError();   // clear sticky error, use proven chain
        hipLaunchKernelGGL(k1_fill_gemm,    dim3(GEMM_BLOCKS + 8192), dim3(256), 0, stream,
                           x, wgT4, out, expert_id, gate1, keys, me_part, hist_part);
        hipLaunchKernelGGL(k2_rank_scalars, dim3(257),                dim3(256), 0, stream,
                           keys, expert_id, me_part, hist_part, key2, out);
        hipLaunchKernelGGL(k3_loc_scatter,  dim3(256),                dim3(256), 0, stream,
                           key2, gate1, out);
    }
}

// Round 8
// 735.427 us; speedup vs baseline: 1.1578x; 1.0905x over previous
//
#include <hip/hip_runtime.h>
#include <stdint.h>

// Problem constants (static per reference)
#define S_TOK   8192
#define MODEL_D 1024
#define N_EXP   64
#define CAP     128         // max(ceil(8192/64*1.0), 8)
#define SHIFT   4096        // int(S * 0.5)
#define SLAB    (N_EXP * CAP)           // 8192 floats per token slab
#define CDSIZE  ((size_t)S_TOK * SLAB)  // 67108864
#define OUT_FILL4 33554448              // float4 count covering out[0..134217792)

#define GEMM_BLOCKS 512
#define TPB         16                  // tokens per gemm block
#define FILL_BLOCKS 4096                // 8192 float4 (128 KB) per block

// d_out layout (float32): [l_aux(1) | combine(CDSIZE) | dispatch(CDSIZE) | exp_counts(64) | unrouted(1)]
// Fill covers out[0..134217792); exp_counts[63] + unrouted are written
// unconditionally by the scalar block of k2.

// ws offsets (bytes)
#define OFF_EXPERT   0          // int[8192]
#define OFF_GATE     32768      // float[8192]   max-gate value (=1/Z)
#define OFF_KEY      65536      // uint[8192]    sortable importance key
#define OFF_KEY2     98304      // uint[8192]    (expert<<13)|pos
#define OFF_MEPART   131072     // float[512][64] per-block gate column sums
#define OFF_HIST     262144     // int[512][64]   per-block argmax histograms
#define OFF_WGT      393216     // float[256][64][4] repacked weights [d/4][e][d%4]

__device__ __forceinline__ unsigned f2key(float f) {
    // monotonic float->uint transform (ascending float == ascending uint)
    unsigned b = __float_as_uint(f);
    return (b & 0x80000000u) ? ~b : (b | 0x80000000u);
}

// N0: weight repack (64 blocks, ~3 µs)
__global__ __launch_bounds__(256) void k0_repack(const float* __restrict__ wg,
                                                 float* __restrict__ wgT4) {
    int id0 = blockIdx.x * 256 + threadIdx.x;
#pragma unroll
    for (int i = 0; i < 4; ++i) {
        int id = id0 + i * 16384;            // 64*1024 total
        int e = id >> 10;
        int d = id & 1023;
        wgT4[((d >> 2) * 64 + e) * 4 + (d & 3)] = wg[id];
    }
}

// N1: standalone zero-fill of out — rocclr-fill-style: plain float4 stores,
// contiguous 128 KB per block, 4x unrolled, no LDS, minimal VGPR.
// This kernel is the measurement: its rocprof row gives d_out write BW directly.
__global__ __launch_bounds__(256) void k_fill(float4* __restrict__ out4) {
    const float4 z = make_float4(0.f, 0.f, 0.f, 0.f);
    const int tid = threadIdx.x;
    const size_t b0 = (size_t)blockIdx.x * 8192;   // 8192 float4 per block
#pragma unroll
    for (int it = 0; it < 32; it += 4) {
        out4[b0 + (size_t)(it + 0) * 256 + tid] = z;
        out4[b0 + (size_t)(it + 1) * 256 + tid] = z;
        out4[b0 + (size_t)(it + 2) * 256 + tid] = z;
        out4[b0 + (size_t)(it + 3) * 256 + tid] = z;
    }
    if (blockIdx.x == 0 && tid < 16)               // tail: 33554448 - 4096*8192 = 16
        out4[(size_t)FILL_BLOCKS * 8192 + tid] = z;
}

// N2: gate GEMM + softmax/argmax/key + per-block me & histogram partials.
__global__ __launch_bounds__(256) void k1_gemm(
    const float* __restrict__ x, const float* __restrict__ wgT4,
    int* __restrict__ expert_id, float* __restrict__ gate1,
    unsigned* __restrict__ keys, float* __restrict__ me_part,
    int* __restrict__ hist_part)
{
    __shared__ float xs[TPB][256];   // 16 KB x chunk tile
    __shared__ float lg[TPB][65];    // logits tile, padded
    __shared__ float mrow[TPB], zrow[TPB];
    __shared__ int   exrow[TPB];
    __shared__ int   hist[64];
    __shared__ float mep[4][64];

    const int tid  = threadIdx.x;
    const int lane = tid & 63;       // expert index
    const int wv   = tid >> 6;
    const int tok0 = blockIdx.x * TPB;

    const float4* xg  = (const float4*)x;
    const float4* wg4 = (const float4*)wgT4;

    float acc[4] = {0.f, 0.f, 0.f, 0.f};
    for (int chunk = 0; chunk < 4; ++chunk) {
        __syncthreads();
#pragma unroll
        for (int i = 0; i < 4; ++i) {
            int linear = tid + 256 * i;          // 0..1023
            int t  = linear >> 6;
            int c4 = linear & 63;
            ((float4*)xs)[t * 64 + c4] = xg[(size_t)(tok0 + t) * 256 + chunk * 64 + c4];
        }
        __syncthreads();
#pragma unroll 4
        for (int dd = 0; dd < 256; dd += 4) {
            int d = chunk * 256 + dd;
            float4 w = wg4[(d >> 2) * 64 + lane];    // coalesced across lanes
#pragma unroll
            for (int t = 0; t < 4; ++t) {
                float4 xv = *(const float4*)&xs[wv * 4 + t][dd];  // LDS broadcast
                acc[t] = fmaf(xv.x, w.x, acc[t]);
                acc[t] = fmaf(xv.y, w.y, acc[t]);
                acc[t] = fmaf(xv.z, w.z, acc[t]);
                acc[t] = fmaf(xv.w, w.w, acc[t]);
            }
        }
    }
#pragma unroll
    for (int t = 0; t < 4; ++t) lg[wv * 4 + t][lane] = acc[t];
    __syncthreads();

    if (tid < 64) hist[tid] = 0;
    if (tid < TPB) {
        const int t = tid;
        float m = lg[t][0]; int am = 0;
        for (int e = 1; e < 64; ++e) {
            float v = lg[t][e];
            if (v > m) { m = v; am = e; }   // strict >: first-occurrence argmax (jnp)
        }
        float z = 0.f;
        for (int e = 0; e < 64; ++e) z += expf(lg[t][e] - m);
        float rz = 1.0f / z;                // = max gate value
        mrow[t] = m; zrow[t] = rz; exrow[t] = am;
        int sG = tok0 + t;
        expert_id[sG] = am;
        gate1[sG] = rz;
        keys[sG] = f2key(-rz);              // importance = -maxgate, ascending
    }
    __syncthreads();

    if (tid < TPB) atomicAdd(&hist[exrow[tid]], 1);
    {   // me column partials
        const int e = tid & 63, tg = tid >> 6;
        float p = 0.f;
        for (int t = tg; t < TPB; t += 4) p += expf(lg[t][e] - mrow[t]) * zrow[t];
        mep[tg][e] = p;
    }
    __syncthreads();

    if (tid < 64) {
        me_part[blockIdx.x * 64 + tid] = mep[0][tid] + mep[1][tid]
                                       + mep[2][tid] + mep[3][tid];
        hist_part[blockIdx.x * 64 + tid] = hist[tid];
    }
}

// N3: blocks 0..255 — global rank -> key2; block 256 — scalar outputs.
__global__ __launch_bounds__(256) void k2_rank_scalars(
    const unsigned* __restrict__ keys, const int* __restrict__ expert_id,
    const float* __restrict__ me_part, const int* __restrict__ hist_part,
    unsigned* __restrict__ key2, float* __restrict__ out)
{
    const int tid = threadIdx.x;
    if (blockIdx.x == 256) {
        __shared__ float msum[4][64];
        __shared__ int   hsum[4][64];
        __shared__ float contrib[64];
        __shared__ int   keep[64];
        const int e = tid & 63, qt = tid >> 6;
        float ms = 0.f; int hs = 0;
        for (int p = qt * 128; p < qt * 128 + 128; ++p) {
            ms += me_part[p * 64 + e];
            hs += hist_part[p * 64 + e];
        }
        msum[qt][e] = ms; hsum[qt][e] = hs;
        __syncthreads();
        if (tid < 64) {
            float m = msum[0][tid] + msum[1][tid] + msum[2][tid] + msum[3][tid];
            int   h = hsum[0][tid] + hsum[1][tid] + hsum[2][tid] + hsum[3][tid];
            out[1 + 2 * CDSIZE + tid] = (float)h;                          // exp_counts
            contrib[tid] = (m * (1.0f / S_TOK)) * ((float)h * (1.0f / S_TOK));
            keep[tid] = (h < CAP) ? h : CAP;
        }
        __syncthreads();
        if (tid == 0) {
            // dropped = S - sum_e min(count_e, CAP): within-expert ranks are a
            // bijection 0..count_e-1, so drops are exactly the overflow.
            float sum = 0.f; int kept = 0;
            for (int i = 0; i < 64; ++i) { sum += contrib[i]; kept += keep[i]; }
            out[0] = sum * (float)N_EXP * 0.01f;                           // l_aux
            out[1 + 2 * CDSIZE + 64] = (float)(S_TOK - kept) * (1.0f / S_TOK); // unrouted
        }
        return;
    }

    __shared__ uint4 k4[2048];   // all 8192 keys, 32 KB
    const uint4* kg = (const uint4*)keys;
    for (int i = tid; i < 2048; i += 256) k4[i] = kg[i];
    __syncthreads();

    const int sl = tid >> 3, part = tid & 7;   // 32 tokens/block, 8 scan-threads/token
    const int sG = blockIdx.x * 32 + sl;
    const unsigned myk = ((const unsigned*)k4)[sG];
    int cnt = 0;
    const int qbase = part * 256;
    for (int q = 0; q < 256; ++q) {
        int qq = (q + part) & 255;             // bank-phase swizzle
        uint4 v = k4[qbase + qq];
        int j = (qbase + qq) * 4;
        cnt += (v.x < myk) || (v.x == myk && (j + 0) < sG);
        cnt += (v.y < myk) || (v.y == myk && (j + 1) < sG);
        cnt += (v.z < myk) || (v.z == myk && (j + 2) < sG);
        cnt += (v.w < myk) || (v.w == myk && (j + 3) < sG);
    }
    cnt += __shfl_down(cnt, 4);
    cnt += __shfl_down(cnt, 2);
    cnt += __shfl_down(cnt, 1);
    if (part == 0) {
        int pos = (cnt + SHIFT) & (S_TOK - 1);
        key2[sG] = ((unsigned)expert_id[sG] << 13) | (unsigned)pos;
    }
}

// N4: within-expert loc + one-hot scatter into the pre-zeroed out.
__global__ __launch_bounds__(256) void k3_loc_scatter(const unsigned* __restrict__ key2,
                                                      const float* __restrict__ gate1,
                                                      float* __restrict__ out)
{
    __shared__ uint4 k4[2048];
    const int tid = threadIdx.x;
    const uint4* kg = (const uint4*)key2;
    for (int i = tid; i < 2048; i += 256) k4[i] = kg[i];
    __syncthreads();

    const int sl = tid >> 3, part = tid & 7;
    const int sG = blockIdx.x * 32 + sl;
    const unsigned myk = ((const unsigned*)k4)[sG];
    const unsigned lo = myk & ~8191u;   // expert<<13
    int cnt = 0;
    const int qbase = part * 256;
    for (int q = 0; q < 256; ++q) {
        int qq = (q + part) & 255;
        uint4 v = k4[qbase + qq];
        cnt += (v.x >= lo) && (v.x < myk);
        cnt += (v.y >= lo) && (v.y < myk);
        cnt += (v.z >= lo) && (v.z < myk);
        cnt += (v.w >= lo) && (v.w < myk);
    }
    cnt += __shfl_down(cnt, 4);
    cnt += __shfl_down(cnt, 2);
    cnt += __shfl_down(cnt, 1);
    if (part == 0 && cnt < CAP) {
        unsigned e = myk >> 13;
        size_t idx = 1 + (size_t)sG * SLAB + (size_t)e * CAP + (unsigned)cnt;
        out[idx] = gate1[sG];            // combine_weights one-hot
        out[idx + CDSIZE] = 1.0f;        // dispatch_mask one-hot
    }
}

extern "C" void kernel_launch(void* const* d_in, const int* in_sizes, int n_in,
                              void* d_out, int out_size, void* d_ws, size_t ws_size,
                              hipStream_t stream) {
    (void)in_sizes; (void)n_in; (void)out_size; (void)ws_size;
    const float* x  = (const float*)d_in[0];
    const float* wg = (const float*)d_in[1];
    float* out = (float*)d_out;
    char* ws = (char*)d_ws;

    float*    wgT4      = (float*)(ws + OFF_WGT);
    int*      expert_id = (int*)(ws + OFF_EXPERT);
    float*    gate1     = (float*)(ws + OFF_GATE);
    unsigned* keys      = (unsigned*)(ws + OFF_KEY);
    unsigned* key2      = (unsigned*)(ws + OFF_KEY2);
    float*    me_part   = (float*)(ws + OFF_MEPART);
    int*      hist_part = (int*)(ws + OFF_HIST);

    hipLaunchKernelGGL(k0_repack,       dim3(64),          dim3(256), 0, stream, wg, wgT4);
    hipLaunchKernelGGL(k_fill,          dim3(FILL_BLOCKS), dim3(256), 0, stream, (float4*)out);
    hipLaunchKernelGGL(k1_gemm,         dim3(GEMM_BLOCKS), dim3(256), 0, stream,
                       x, wgT4, expert_id, gate1, keys, me_part, hist_part);
    hipLaunchKernelGGL(k2_rank_scalars, dim3(257),         dim3(256), 0, stream,
                       keys, expert_id, me_part, hist_part, key2, out);
    hipLaunchKernelGGL(k3_loc_scatter,  dim3(256),         dim3(256), 0, stream,
                       key2, gate1, out);
}